// Round 1
// baseline (839.203 us; speedup 1.0000x reference)
//
#include <hip/hip_runtime.h>

typedef __attribute__((ext_vector_type(8))) short short8;
typedef __attribute__((ext_vector_type(4))) float floatx4;

#define SCALE 0.17677669529663687f   // 32^-0.5
#define RSTR 136   // bf16 LDS row stride (elements) — 272B, +16B pad kills b128 bank conflicts
#define QSTR 132   // q_s row stride (floats)

__device__ __forceinline__ unsigned f2bf_bits(float f) {
  union { float f; unsigned u; } v; v.f = f;
  unsigned u = v.u;
  return ((u + 0x7fffu + ((u >> 16) & 1u)) >> 16) & 0xffffu;  // RNE f32->bf16
}

// LayerNorm of one 128-float row by one wave: lane handles elements 2L, 2L+1.
__device__ __forceinline__ void ln_row_wave(const float* __restrict__ src,
                                            short* dst, int lane,
                                            float g0, float g1, float b0, float b1) {
  float2 v = reinterpret_cast<const float2*>(src)[lane];
  float s1 = v.x + v.y;
  float s2 = v.x * v.x + v.y * v.y;
#pragma unroll
  for (int m = 1; m < 64; m <<= 1) {
    s1 += __shfl_xor(s1, m, 64);
    s2 += __shfl_xor(s2, m, 64);
  }
  float mu  = s1 * (1.0f / 128.0f);
  float var = fmaf(-mu, mu, s2 * (1.0f / 128.0f));
  float inv = rsqrtf(var + 1e-5f);
  float na = fmaf((v.x - mu) * inv, g0, b0);
  float nb = fmaf((v.y - mu) * inv, g1, b1);
  unsigned packed = f2bf_bits(na) | (f2bf_bits(nb) << 16);
  reinterpret_cast<unsigned*>(dst)[lane] = packed;  // shorts 2L,2L+1
}

// Pass 0: cast+transpose weights to bf16 W^T[n][k] so B-fragments are 16B/lane loads.
__global__ void prep_weights(const float* __restrict__ Wq,
                             const float* __restrict__ Wkv,
                             const float* __restrict__ Wo,
                             short* __restrict__ wqT, short* __restrict__ wkvT,
                             short* __restrict__ woT) {
  int t = blockIdx.x * 256 + threadIdx.x;
  if (t < 16384) {                       // WqT[n*128+k] = Wq[k][n]
    int n = t >> 7, k = t & 127;
    wqT[t] = (short)f2bf_bits(Wq[k * 128 + n]);
  } else if (t < 49152) {                // WkvT[n*128+k] = Wkv[k][n], n<256
    int u = t - 16384; int n = u >> 7, k = u & 127;
    wkvT[u] = (short)f2bf_bits(Wkv[k * 256 + n]);
  } else if (t < 65536) {                // WoT[n*128+k] = Wo[k][n]
    int u = t - 49152; int n = u >> 7, k = u & 127;
    woT[u] = (short)f2bf_bits(Wo[k * 128 + n]);
  }
}

// One block = 16 points. Wave w owns head w (q/k/v cols [w*32,w*32+32)), so
// attention is wave-local: shuffle reductions, no kv LDS round-trip.
__global__ __launch_bounds__(256) void fused_ca(
    const float* __restrict__ x, const float* __restrict__ y,
    const float* __restrict__ ln_g, const float* __restrict__ ln_b,
    const short* __restrict__ wqT, const short* __restrict__ wkvT,
    const short* __restrict__ woT, const float* __restrict__ bo,
    float* __restrict__ out) {
  __shared__ short Xn[16 * RSTR];      // normalized x rows (bf16, A-layout rows)
  __shared__ short Yb[2][16 * RSTR];   // double-buffered normalized y rows of one point
  __shared__ short Os[16 * RSTR];      // attention outputs (bf16)
  __shared__ float Qs[16 * QSTR];      // q (f32)

  const int tid  = threadIdx.x;
  const int w    = tid >> 6;           // wave id = head id
  const int lane = tid & 63;
  const int l16  = lane & 15;
  const int quad = lane >> 4;
  const long gbase = (long)blockIdx.x * 16;

  // per-lane LN affine constants (lane always handles cols 2L, 2L+1)
  const float lg0 = ln_g[2 * lane], lg1 = ln_g[2 * lane + 1];
  const float lb0 = ln_b[2 * lane], lb1 = ln_b[2 * lane + 1];

  // ---- register-cache Wkv B-fragments: 4 col-tiles (k0,k1,v0,v1) x 4 k-steps ----
  short8 wf[4][4];
#pragma unroll
  for (int ct = 0; ct < 4; ++ct) {
    int n0 = (ct < 2) ? (w * 32 + ct * 16) : (128 + w * 32 + (ct - 2) * 16);
#pragma unroll
    for (int ks = 0; ks < 4; ++ks)
      wf[ct][ks] = *reinterpret_cast<const short8*>(
          wkvT + (n0 + l16) * 128 + ks * 32 + quad * 8);
  }

  // ---- LN: 16 x-rows + y-rows of point 0 (wave w does rows w, w+4, w+8, w+12) ----
#pragma unroll
  for (int j = 0; j < 4; ++j) {
    int r = w + 4 * j;
    ln_row_wave(x + (gbase + r) * 128, Xn + r * RSTR, lane, lg0, lg1, lb0, lb1);
  }
#pragma unroll
  for (int j = 0; j < 4; ++j) {
    int r = w + 4 * j;
    ln_row_wave(y + ((gbase + 0) * 16 + r) * 128, Yb[0] + r * RSTR,
                lane, lg0, lg1, lb0, lb1);
  }
  __syncthreads();

  // ---- Q GEMM: Xn[16 pts,128] @ Wq -> Qs  (wave w computes cols [w*32, w*32+32)) ----
  {
    short8 af[4];
#pragma unroll
    for (int ks = 0; ks < 4; ++ks)
      af[ks] = *reinterpret_cast<const short8*>(Xn + l16 * RSTR + ks * 32 + quad * 8);
#pragma unroll
    for (int t = 0; t < 2; ++t) {
      floatx4 acc = {0.f, 0.f, 0.f, 0.f};
      int n0 = w * 32 + t * 16;
#pragma unroll
      for (int ks = 0; ks < 4; ++ks) {
        short8 bf = *reinterpret_cast<const short8*>(
            wqT + (n0 + l16) * 128 + ks * 32 + quad * 8);
        acc = __builtin_amdgcn_mfma_f32_16x16x32_bf16(af[ks], bf, acc, 0, 0, 0);
      }
#pragma unroll
      for (int r = 0; r < 4; ++r)
        Qs[(quad * 4 + r) * QSTR + n0 + l16] = acc[r];   // row = point index
    }
  }

  // ---- main loop over the block's 16 points ----
  for (int p = 0; p < 16; ++p) {
    __syncthreads();   // Yb[p&1] ready; previous readers of Yb[(p+1)&1] done
    if (p + 1 < 16) {  // LN next point's y rows into the other buffer
#pragma unroll
      for (int j = 0; j < 4; ++j) {
        int r = w + 4 * j;
        ln_row_wave(y + ((gbase + p + 1) * 16 + r) * 128,
                    Yb[(p + 1) & 1] + r * RSTR, lane, lg0, lg1, lb0, lb1);
      }
    }
    // KV GEMM: Yn[16,128] @ Wkv -> wave-local k,v tiles (C-layout: i=quad*4+r, col=l16)
    const short* yb = Yb[p & 1];
    short8 af[4];
#pragma unroll
    for (int ks = 0; ks < 4; ++ks)
      af[ks] = *reinterpret_cast<const short8*>(yb + l16 * RSTR + ks * 32 + quad * 8);
    floatx4 acc[4];
#pragma unroll
    for (int ct = 0; ct < 4; ++ct) {
      acc[ct] = {0.f, 0.f, 0.f, 0.f};
#pragma unroll
      for (int ks = 0; ks < 4; ++ks)
        acc[ct] = __builtin_amdgcn_mfma_f32_16x16x32_bf16(af[ks], wf[ct][ks],
                                                          acc[ct], 0, 0, 0);
    }
    // ---- attention for head w, all in-wave ----
    float qv0 = Qs[p * QSTR + w * 32 + l16];
    float qv1 = Qs[p * QSTR + w * 32 + 16 + l16];
    float part[4];
#pragma unroll
    for (int r = 0; r < 4; ++r)
      part[r] = qv0 * acc[0][r] + qv1 * acc[1][r];   // partial over lane's 2 cols
#pragma unroll
    for (int m = 1; m <= 8; m <<= 1) {               // reduce over 16 d-lanes
#pragma unroll
      for (int r = 0; r < 4; ++r) part[r] += __shfl_xor(part[r], m, 64);
    }
#pragma unroll
    for (int r = 0; r < 4; ++r) part[r] *= SCALE;    // dots[i=quad*4+r]
    float mx = fmaxf(fmaxf(part[0], part[1]), fmaxf(part[2], part[3]));
    mx = fmaxf(mx, __shfl_xor(mx, 16, 64));
    mx = fmaxf(mx, __shfl_xor(mx, 32, 64));
    float e[4], s = 0.f;
#pragma unroll
    for (int r = 0; r < 4; ++r) { e[r] = __expf(part[r] - mx); s += e[r]; }
    s += __shfl_xor(s, 16, 64);
    s += __shfl_xor(s, 32, 64);
    float rs = 1.0f / s;
    float o0 = 0.f, o1 = 0.f;
#pragma unroll
    for (int r = 0; r < 4; ++r) {
      float a = e[r] * rs;
      o0 += a * acc[2][r];       // v cols w*32 + l16
      o1 += a * acc[3][r];       // v cols w*32 + 16 + l16
    }
    o0 += __shfl_xor(o0, 16, 64); o0 += __shfl_xor(o0, 32, 64);
    o1 += __shfl_xor(o1, 16, 64); o1 += __shfl_xor(o1, 32, 64);
    if (quad == 0) {
      Os[p * RSTR + w * 32 + l16]      = (short)f2bf_bits(o0);
      Os[p * RSTR + w * 32 + 16 + l16] = (short)f2bf_bits(o1);
    }
  }
  __syncthreads();

  // ---- output GEMM: Os[16 pts,128] @ Wo + bo + x -> out ----
  {
    short8 af[4];
#pragma unroll
    for (int ks = 0; ks < 4; ++ks)
      af[ks] = *reinterpret_cast<const short8*>(Os + l16 * RSTR + ks * 32 + quad * 8);
#pragma unroll
    for (int t = 0; t < 2; ++t) {
      floatx4 acc = {0.f, 0.f, 0.f, 0.f};
      int n0 = w * 32 + t * 16;
#pragma unroll
      for (int ks = 0; ks < 4; ++ks) {
        short8 bf = *reinterpret_cast<const short8*>(
            woT + (n0 + l16) * 128 + ks * 32 + quad * 8);
        acc = __builtin_amdgcn_mfma_f32_16x16x32_bf16(af[ks], bf, acc, 0, 0, 0);
      }
      float bias = bo[n0 + l16];
#pragma unroll
      for (int r = 0; r < 4; ++r) {
        long g = gbase + quad * 4 + r;   // C row = point index
        out[g * 128 + n0 + l16] = acc[r] + bias + x[g * 128 + n0 + l16];
      }
    }
  }
}

extern "C" void kernel_launch(void* const* d_in, const int* in_sizes, int n_in,
                              void* d_out, int out_size, void* d_ws, size_t ws_size,
                              hipStream_t stream) {
  const float* x    = (const float*)d_in[0];
  const float* y    = (const float*)d_in[1];
  const float* ln_g = (const float*)d_in[2];
  const float* ln_b = (const float*)d_in[3];
  const float* Wq   = (const float*)d_in[4];
  const float* Wkv  = (const float*)d_in[5];
  const float* Wo   = (const float*)d_in[6];
  const float* bo   = (const float*)d_in[7];
  float* out = (float*)d_out;

  short* wqT  = (short*)d_ws;        // 16384 bf16
  short* wkvT = wqT + 16384;         // 32768 bf16
  short* woT  = wkvT + 32768;        // 16384 bf16

  prep_weights<<<256, 256, 0, stream>>>(Wq, Wkv, Wo, wqT, wkvT, woT);
  fused_ca<<<4096, 256, 0, stream>>>(x, y, ln_g, ln_b, wqT, wkvT, woT, bo, out);
}